// Round 9
// baseline (81.728 us; speedup 1.0000x reference)
//
#include <hip/hip_runtime.h>
#include <math.h>

// Problem constants
#define BB 32
#define TT 4096
#define DD 512
#define SS 256
#define SEG 64            // wave-segments per batch (each wave: 64 rows)
#define GRP 32            // groups of 2 rows per wave (GRP*2*SEG == TT)
static constexpr float INV_SCALE = 10.0f;   // 1/0.1

// ---------------------------------------------------------------------------
// Kernel 1: q = silu(t_star*W1+b1) @ W2 + b2.
// grid = B*8 blocks (b, jg); block 512 = 64 outputs x 8 k-groups.
// ---------------------------------------------------------------------------
__global__ __launch_bounds__(512) void k_q(
    const float* __restrict__ t_star, const float* __restrict__ W1,
    const float* __restrict__ b1, const float* __restrict__ W2,
    const float* __restrict__ b2, float* __restrict__ q) {
  const int b   = blockIdx.x >> 3;
  const int jg  = blockIdx.x & 7;
  const int tid = threadIdx.x;
  const int di  = tid & 63;
  const int kg  = tid >> 6;
  __shared__ float h[DD];
  __shared__ float red[8][64];
  {
    float x = t_star[b] * W1[tid] + b1[tid];
    h[tid] = x / (1.0f + __expf(-x));     // silu
  }
  __syncthreads();
  const float* w = W2 + jg * 64 + di;
  float acc = 0.0f;
#pragma unroll 8
  for (int kk = 0; kk < 64; ++kk) {
    const int k = kg * 64 + kk;
    acc += h[k] * w[(size_t)k * DD];
  }
  red[kg][di] = acc;
  __syncthreads();
  if (tid < 64) {
    float s = 0.0f;
#pragma unroll
    for (int g = 0; g < 8; ++g) s += red[g][tid];
    q[b * DD + jg * 64 + tid] = s + b2[jg * 64 + tid];
  }
}

// ---------------------------------------------------------------------------
// Kernel 2: LDS-staged flash pooling (R7 inner loop, single-round grid).
// Each WAVE owns 64 rows (one segment) as 32 groups of 2 rows via a 3-slot
// LDS ring filled by global_load_lds; depth-2 prefetch, vmcnt(8) steady.
// 48 KB/block -> 3 blocks/CU capacity; grid = 512 blocks <= 768 resident
// slots: ALL blocks co-resident, zero occupancy tail, single round.
// Row mapping r = 2*(g*SEG+s): coherent 128-row address front per batch.
// No __syncthreads, no cross-wave LDS sharing.
// ---------------------------------------------------------------------------
#define GLDS(gp, lp)                                                        \
  __builtin_amdgcn_global_load_lds(                                         \
      (const __attribute__((address_space(1))) void*)(gp),                  \
      (__attribute__((address_space(3))) void*)(lp), 16, 0, 0)

__global__ __launch_bounds__(256) void k_fused(
    const float* __restrict__ ctx, const float* __restrict__ q,
    const float* __restrict__ t_star, const float* __restrict__ t_ctx,
    float* __restrict__ part_pool,    // [B*SEG*DD]
    float* __restrict__ part_ms) {    // [B*SEG*2]  (m, l)
  __shared__ __align__(16) float lds[4][3][2 * DD];   // 48 KB: [wave][slot][2 rows]
  const int wid  = threadIdx.x >> 6;
  const int lane = threadIdx.x & 63;
  const int w    = blockIdx.x * 4 + wid;   // global wave id
  const int b    = w >> 6;                 // / SEG
  const int s    = w & 63;                 // % SEG

  const float4* qp = (const float4*)(q + b * DD);
  const float4 q0 = qp[lane];
  const float4 q1 = qp[64 + lane];
  const float ts = t_star[b];
  // lane g (g<32) holds the time-bias pair for its group's rows
  const float2 tc = *(const float2*)(t_ctx + b * TT + ((lane & 31) * 2 * SEG + 2 * s));
  const float tbx = -fabsf(ts - tc.x) * INV_SCALE;
  const float tby = -fabsf(ts - tc.y) * INV_SCALE;

  float m = -INFINITY, l = 0.0f;
  float4 p0 = {0, 0, 0, 0}, p1 = {0, 0, 0, 0};

  const float* cb = ctx + ((size_t)b * TT + 2 * s) * DD;   // group-0 base

  // prologue: stage groups 0,1 into slots 0,1
#pragma unroll
  for (int g = 0; g < 2; ++g) {
    const float* gb = cb + (size_t)g * 2 * SEG * DD;
    float* sb = &lds[wid][g][0];
#pragma unroll
    for (int piece = 0; piece < 4; ++piece)
      GLDS(gb + piece * 256 + lane * 4, sb + piece * 256);
  }

#pragma unroll
  for (int g = 0; g < GRP; ++g) {
    if (g + 2 < GRP) {
      const float* gb = cb + (size_t)(g + 2) * 2 * SEG * DD;
      float* sb = &lds[wid][(g + 2) % 3][0];
#pragma unroll
      for (int piece = 0; piece < 4; ++piece)
        GLDS(gb + piece * 256 + lane * 4, sb + piece * 256);
      asm volatile("s_waitcnt vmcnt(8)" ::: "memory");   // group g resident
    } else if (g + 2 == GRP) {
      asm volatile("s_waitcnt vmcnt(4)" ::: "memory");
    } else {
      asm volatile("s_waitcnt vmcnt(0)" ::: "memory");
    }

    const float4* sf = (const float4*)&lds[wid][g % 3][0];
    const float4 x0 = sf[lane];        // row0 dims [lane*4 .. +3]
    const float4 x1 = sf[64 + lane];   // row0 dims [256+lane*4 ..]
    const float4 y0 = sf[128 + lane];  // row1
    const float4 y1 = sf[192 + lane];

    float s0 = x0.x * q0.x + x0.y * q0.y + x0.z * q0.z + x0.w * q0.w +
               x1.x * q1.x + x1.y * q1.y + x1.z * q1.z + x1.w * q1.w;
    float s1 = y0.x * q0.x + y0.y * q0.y + y0.z * q0.z + y0.w * q0.w +
               y1.x * q1.x + y1.y * q1.y + y1.z * q1.z + y1.w * q1.w;
#pragma unroll
    for (int off = 32; off > 0; off >>= 1) {
      s0 += __shfl_xor(s0, off);
      s1 += __shfl_xor(s1, off);
    }
    s0 += __shfl(tbx, g);
    s1 += __shfl(tby, g);

    const float gm = fmaxf(s0, s1);
    const float nm = fmaxf(m, gm);
    const float sc = __expf(m - nm);   // g==0: exp(-inf)=0, p=l=0 anyway
    m = nm;
    const float e0 = __expf(s0 - m);
    const float e1 = __expf(s1 - m);
    l = l * sc + e0 + e1;
    p0.x = p0.x * sc + e0 * x0.x + e1 * y0.x;
    p0.y = p0.y * sc + e0 * x0.y + e1 * y0.y;
    p0.z = p0.z * sc + e0 * x0.z + e1 * y0.z;
    p0.w = p0.w * sc + e0 * x0.w + e1 * y0.w;
    p1.x = p1.x * sc + e0 * x1.x + e1 * y1.x;
    p1.y = p1.y * sc + e0 * x1.y + e1 * y1.y;
    p1.z = p1.z * sc + e0 * x1.z + e1 * y1.z;
    p1.w = p1.w * sc + e0 * x1.w + e1 * y1.w;
  }

  float4* pp = (float4*)(part_pool + (size_t)w * DD);
  pp[lane] = p0;
  pp[64 + lane] = p1;
  if (lane == 0) {
    part_ms[w * 2 + 0] = m;
    part_ms[w * 2 + 1] = l;
  }
}

// ---------------------------------------------------------------------------
// Kernel 3: merge segment partials into normalized pool[b,:].
// grid = B*4 (b, dg); block 512 = 128 d x 4 chunk-groups. part_pool read ONCE.
// ---------------------------------------------------------------------------
__global__ __launch_bounds__(512) void k_merge(
    const float* __restrict__ part_pool, const float* __restrict__ part_ms,
    float* __restrict__ pool) {
  const int b   = blockIdx.x >> 2;
  const int dg  = blockIdx.x & 3;
  const int tid = threadIdx.x;
  const int lane = tid & 63;
  const int base = b * SEG;
  __shared__ float scl[SEG];
  __shared__ float red[4][128];

  // wave-parallel global (M, Z) over 64 segments (each wave redundantly)
  const float mv = part_ms[(base + lane) * 2 + 0];
  const float lv = part_ms[(base + lane) * 2 + 1];
  float M = mv;
#pragma unroll
  for (int off = 32; off > 0; off >>= 1) M = fmaxf(M, __shfl_xor(M, off));
  float Z = __expf(mv - M) * lv;
#pragma unroll
  for (int off = 32; off > 0; off >>= 1) Z += __shfl_xor(Z, off);
  const float invZ = 1.0f / Z;
  if (tid < SEG) scl[tid] = __expf(part_ms[(base + tid) * 2] - M);
  __syncthreads();

  const int dl = tid & 127;
  const int cg = tid >> 7;
  float acc = 0.0f;
#pragma unroll 8
  for (int i = 0; i < 16; ++i) {
    const int c = cg * 16 + i;
    acc += scl[c] * part_pool[((size_t)base + c) * DD + dg * 128 + dl];
  }
  red[cg][dl] = acc;
  __syncthreads();
  if (tid < 128)
    pool[b * DD + dg * 128 + tid] =
        (red[0][tid] + red[1][tid] + red[2][tid] + red[3][tid]) * invZ;
}

// ---------------------------------------------------------------------------
// Kernel 4: out = pool @ Wout + bout. grid = B*8 (b,jg); block 256 = 4kg x 64j.
// ---------------------------------------------------------------------------
__global__ __launch_bounds__(256) void k_out(
    const float* __restrict__ pool, const float* __restrict__ Wout,
    const float* __restrict__ bout, float* __restrict__ out) {
  const int b   = blockIdx.x >> 3;
  const int jg  = blockIdx.x & 7;
  const int tid = threadIdx.x;
  const int kg  = tid >> 6;
  const int j   = tid & 63;
  const int jc  = jg * 64 + j;
  __shared__ float p[DD];
  __shared__ float red[4][64];

  p[tid] = pool[b * DD + tid];
  p[tid + 256] = pool[b * DD + 256 + tid];
  __syncthreads();

  float acc = 0.0f;
#pragma unroll 8
  for (int kk = 0; kk < 128; ++kk) {
    const int k = kg * 128 + kk;
    acc += p[k] * Wout[(size_t)k * DD + jc];
  }
  red[kg][j] = acc;
  __syncthreads();
  if (tid < 64) {
    const int jj = jg * 64 + tid;
    float o = red[0][tid] + red[1][tid] + red[2][tid] + red[3][tid] + bout[jj];
    if (jj < SS) out[b * SS + jj] = o;                       // mu
    else         out[BB * SS + b * SS + (jj - SS)] = o;      // log_sigma
  }
}

// ---------------------------------------------------------------------------
extern "C" void kernel_launch(void* const* d_in, const int* in_sizes, int n_in,
                              void* d_out, int out_size, void* d_ws, size_t ws_size,
                              hipStream_t stream) {
  const float* ctx    = (const float*)d_in[0];   // (B,T,D)
  const float* t_star = (const float*)d_in[1];   // (B,)
  const float* t_ctx  = (const float*)d_in[2];   // (B,T,1)
  const float* W1     = (const float*)d_in[3];   // (1,D)
  const float* b1     = (const float*)d_in[4];   // (D,)
  const float* W2     = (const float*)d_in[5];   // (D,D)
  const float* b2     = (const float*)d_in[6];   // (D,)
  const float* Wout   = (const float*)d_in[7];   // (D,2S)
  const float* bout   = (const float*)d_in[8];   // (2S,)
  float* out = (float*)d_out;

  float* ws = (float*)d_ws;
  float* q         = ws;                                   // B*D
  float* part_pool = q + (size_t)BB * DD;                  // B*SEG*D  (4 MB)
  float* part_ms   = part_pool + (size_t)BB * SEG * DD;    // B*SEG*2
  float* pool      = part_ms + (size_t)BB * SEG * 2;       // B*D

  k_q<<<BB * 8, 512, 0, stream>>>(t_star, W1, b1, W2, b2, q);
  k_fused<<<BB * SEG / 4, 256, 0, stream>>>(ctx, q, t_star, t_ctx, part_pool, part_ms);
  k_merge<<<BB * 4, 512, 0, stream>>>(part_pool, part_ms, pool);
  k_out<<<BB * 8, 256, 0, stream>>>(pool, Wout, bout, out);
}

// Round 10
// 74.222 us; speedup vs baseline: 1.1011x; 1.1011x over previous
//
#include <hip/hip_runtime.h>
#include <math.h>

// Problem constants
#define BB 32
#define TT 4096
#define DD 512
#define SS 256
#define SEG 128           // wave-segments per batch (each wave: 32 rows)
#define GRP 16            // groups of 2 rows per wave (GRP*2*SEG == TT)
static constexpr float INV_SCALE = 10.0f;   // 1/0.1
static constexpr float DEFER_THR = 28.0f;   // T13 defer-max threshold

// ---------------------------------------------------------------------------
// Kernel 1: q = silu(t_star*W1+b1) @ W2 + b2.
// ---------------------------------------------------------------------------
__global__ __launch_bounds__(512) void k_q(
    const float* __restrict__ t_star, const float* __restrict__ W1,
    const float* __restrict__ b1, const float* __restrict__ W2,
    const float* __restrict__ b2, float* __restrict__ q) {
  const int b   = blockIdx.x >> 3;
  const int jg  = blockIdx.x & 7;
  const int tid = threadIdx.x;
  const int di  = tid & 63;
  const int kg  = tid >> 6;
  __shared__ float h[DD];
  __shared__ float red[8][64];
  {
    float x = t_star[b] * W1[tid] + b1[tid];
    h[tid] = x / (1.0f + __expf(-x));     // silu
  }
  __syncthreads();
  const float* w = W2 + jg * 64 + di;
  float acc = 0.0f;
#pragma unroll 8
  for (int kk = 0; kk < 64; ++kk) {
    const int k = kg * 64 + kk;
    acc += h[k] * w[(size_t)k * DD];
  }
  red[kg][di] = acc;
  __syncthreads();
  if (tid < 64) {
    float s = 0.0f;
#pragma unroll
    for (int g = 0; g < 8; ++g) s += red[g][tid];
    q[b * DD + jg * 64 + tid] = s + b2[jg * 64 + tid];
  }
}

// ---------------------------------------------------------------------------
// Kernel 2: LDS-staged flash pooling. R7 staging skeleton (2-row groups,
// 3-slot ring, depth-2 prefetch, vmcnt(8) steady, 48KB, 1024 blocks) with a
// half-wave row split: lanes 0-31 own row-lo, lanes 32-63 own row-hi.
// Per group: 4 ds_read_b128/lane, 16 dot FMAs, ONE 5-step shuffle reduce for
// both rows, defer-max softmax (rescale only when pm > m + 28).
// Lane li (within half) owns dims {k*128 + li*4 .. +3}, k=0..3.
// No __syncthreads, no cross-wave LDS sharing.
// ---------------------------------------------------------------------------
#define GLDS(gp, lp)                                                        \
  __builtin_amdgcn_global_load_lds(                                         \
      (const __attribute__((address_space(1))) void*)(gp),                  \
      (__attribute__((address_space(3))) void*)(lp), 16, 0, 0)

__global__ __launch_bounds__(256) void k_fused(
    const float* __restrict__ ctx, const float* __restrict__ q,
    const float* __restrict__ t_star, const float* __restrict__ t_ctx,
    float* __restrict__ part_pool,    // [B*SEG*DD]
    float* __restrict__ part_ms) {    // [B*SEG*2]  (m, l)
  __shared__ __align__(16) float lds[4][3][2 * DD];   // 48 KB
  const int wid  = threadIdx.x >> 6;
  const int lane = threadIdx.x & 63;
  const int li   = lane & 31;
  const int half = lane >> 5;
  const int w    = blockIdx.x * 4 + wid;   // global wave id
  const int b    = w >> 7;                 // / SEG
  const int s    = w & 127;                // % SEG

  // q fragment: dims {k*128 + li*4 .. +3}
  const float4* qp = (const float4*)(q + b * DD);
  float4 qf[4];
#pragma unroll
  for (int k = 0; k < 4; ++k) qf[k] = qp[k * 32 + li];

  const float ts = t_star[b];
  // lane (half, li=g) holds the time bias for group g's row of its half
  const float tcv = t_ctx[b * TT + 2 * (li * SEG + s) + half];
  const float tb = -fabsf(ts - tcv) * INV_SCALE;
  // hoist per-group biases for MY half into registers (bpermute, one-time)
  float myb[GRP];
#pragma unroll
  for (int g = 0; g < GRP; ++g) myb[g] = __shfl(tb, (lane & 32) + g);

  float m = -INFINITY, l = 0.0f;
  float4 p[4];
#pragma unroll
  for (int k = 0; k < 4; ++k) p[k] = {0, 0, 0, 0};

  const float* cb = ctx + ((size_t)b * TT + 2 * s) * DD;   // group-0 base

  // prologue: stage groups 0,1 into slots 0,1 (4KB each, rows adjacent)
#pragma unroll
  for (int g = 0; g < 2; ++g) {
    const float* gb = cb + (size_t)g * 2 * SEG * DD;
    float* sb = &lds[wid][g][0];
#pragma unroll
    for (int piece = 0; piece < 4; ++piece)
      GLDS(gb + piece * 256 + lane * 4, sb + piece * 256);
  }

#pragma unroll
  for (int g = 0; g < GRP; ++g) {
    if (g + 2 < GRP) {
      const float* gb = cb + (size_t)(g + 2) * 2 * SEG * DD;
      float* sb = &lds[wid][(g + 2) % 3][0];
#pragma unroll
      for (int piece = 0; piece < 4; ++piece)
        GLDS(gb + piece * 256 + lane * 4, sb + piece * 256);
      asm volatile("s_waitcnt vmcnt(8)" ::: "memory");   // group g resident
    } else if (g + 2 == GRP) {
      asm volatile("s_waitcnt vmcnt(4)" ::: "memory");
    } else {
      asm volatile("s_waitcnt vmcnt(0)" ::: "memory");
    }

    // my half's row: float base = slot + half*512; lane li reads 4 float4s
    const float4* sf = (const float4*)(&lds[wid][g % 3][0] + half * DD);
    float4 x[4];
#pragma unroll
    for (int k = 0; k < 4; ++k) x[k] = sf[k * 32 + li];

    float a = x[0].x * qf[0].x + x[0].y * qf[0].y + x[0].z * qf[0].z + x[0].w * qf[0].w;
#pragma unroll
    for (int k = 1; k < 4; ++k)
      a += x[k].x * qf[k].x + x[k].y * qf[k].y + x[k].z * qf[k].z + x[k].w * qf[k].w;
    // 5-step butterfly within each 32-lane half (both rows reduce at once)
#pragma unroll
    for (int off = 16; off > 0; off >>= 1) a += __shfl_xor(a, off);
    a += myb[g];

    const float pm = fmaxf(a, __shfl_xor(a, 32));   // wave-uniform group max
    if (pm > m + DEFER_THR) {                       // uniform branch (rare)
      const float sc = __expf(m - pm);              // g==0: exp(-inf)=0
      m = pm;
      l *= sc;
#pragma unroll
      for (int k = 0; k < 4; ++k) {
        p[k].x *= sc; p[k].y *= sc; p[k].z *= sc; p[k].w *= sc;
      }
    }
    const float e = __expf(a - m);   // my row's weight (bounded by e^THR)
    l += e;                          // half-sum; combined at end
#pragma unroll
    for (int k = 0; k < 4; ++k) {
      p[k].x += e * x[k].x; p[k].y += e * x[k].y;
      p[k].z += e * x[k].z; p[k].w += e * x[k].w;
    }
  }

  // combine halves (same dim set in both halves)
  l += __shfl_xor(l, 32);
#pragma unroll
  for (int k = 0; k < 4; ++k) {
    p[k].x += __shfl_xor(p[k].x, 32);
    p[k].y += __shfl_xor(p[k].y, 32);
    p[k].z += __shfl_xor(p[k].z, 32);
    p[k].w += __shfl_xor(p[k].w, 32);
  }

  if (lane < 32) {
    float4* pp = (float4*)(part_pool + (size_t)w * DD);
#pragma unroll
    for (int k = 0; k < 4; ++k) pp[k * 32 + li] = p[k];
  }
  if (lane == 0) {
    part_ms[w * 2 + 0] = m;
    part_ms[w * 2 + 1] = l;
  }
}

// ---------------------------------------------------------------------------
// Kernel 3: merge segment partials into normalized pool[b,:].
// grid = B*4 (b, dg); block 512 = 128 d x 4 chunk-groups. part_pool read ONCE.
// ---------------------------------------------------------------------------
__global__ __launch_bounds__(512) void k_merge(
    const float* __restrict__ part_pool, const float* __restrict__ part_ms,
    float* __restrict__ pool) {
  const int b   = blockIdx.x >> 2;
  const int dg  = blockIdx.x & 3;
  const int tid = threadIdx.x;
  const int lane = tid & 63;
  const int base = b * SEG;
  __shared__ float scl[SEG];
  __shared__ float red[4][128];

  // wave-parallel global (M, Z) over 128 segments (each wave redundantly)
  const float mA = part_ms[(base + lane) * 2 + 0];
  const float mB = part_ms[(base + 64 + lane) * 2 + 0];
  const float lA = part_ms[(base + lane) * 2 + 1];
  const float lB = part_ms[(base + 64 + lane) * 2 + 1];
  float M = fmaxf(mA, mB);
#pragma unroll
  for (int off = 32; off > 0; off >>= 1) M = fmaxf(M, __shfl_xor(M, off));
  float Z = __expf(mA - M) * lA + __expf(mB - M) * lB;
#pragma unroll
  for (int off = 32; off > 0; off >>= 1) Z += __shfl_xor(Z, off);
  const float invZ = 1.0f / Z;
  if (tid < SEG) scl[tid] = __expf(part_ms[(base + tid) * 2] - M);
  __syncthreads();

  const int dl = tid & 127;
  const int cg = tid >> 7;
  float acc = 0.0f;
#pragma unroll 8
  for (int i = 0; i < 32; ++i) {
    const int c = cg * 32 + i;
    acc += scl[c] * part_pool[((size_t)base + c) * DD + dg * 128 + dl];
  }
  red[cg][dl] = acc;
  __syncthreads();
  if (tid < 128)
    pool[b * DD + dg * 128 + tid] =
        (red[0][tid] + red[1][tid] + red[2][tid] + red[3][tid]) * invZ;
}

// ---------------------------------------------------------------------------
// Kernel 4: out = pool @ Wout + bout. grid = B*8 (b,jg); block 256 = 4kg x 64j.
// ---------------------------------------------------------------------------
__global__ __launch_bounds__(256) void k_out(
    const float* __restrict__ pool, const float* __restrict__ Wout,
    const float* __restrict__ bout, float* __restrict__ out) {
  const int b   = blockIdx.x >> 3;
  const int jg  = blockIdx.x & 7;
  const int tid = threadIdx.x;
  const int kg  = tid >> 6;
  const int j   = tid & 63;
  const int jc  = jg * 64 + j;
  __shared__ float p[DD];
  __shared__ float red[4][64];

  p[tid] = pool[b * DD + tid];
  p[tid + 256] = pool[b * DD + 256 + tid];
  __syncthreads();

  float acc = 0.0f;
#pragma unroll 8
  for (int kk = 0; kk < 128; ++kk) {
    const int k = kg * 128 + kk;
    acc += p[k] * Wout[(size_t)k * DD + jc];
  }
  red[kg][j] = acc;
  __syncthreads();
  if (tid < 64) {
    const int jj = jg * 64 + tid;
    float o = red[0][tid] + red[1][tid] + red[2][tid] + red[3][tid] + bout[jj];
    if (jj < SS) out[b * SS + jj] = o;                       // mu
    else         out[BB * SS + b * SS + (jj - SS)] = o;      // log_sigma
  }
}

// ---------------------------------------------------------------------------
extern "C" void kernel_launch(void* const* d_in, const int* in_sizes, int n_in,
                              void* d_out, int out_size, void* d_ws, size_t ws_size,
                              hipStream_t stream) {
  const float* ctx    = (const float*)d_in[0];   // (B,T,D)
  const float* t_star = (const float*)d_in[1];   // (B,)
  const float* t_ctx  = (const float*)d_in[2];   // (B,T,1)
  const float* W1     = (const float*)d_in[3];   // (1,D)
  const float* b1     = (const float*)d_in[4];   // (D,)
  const float* W2     = (const float*)d_in[5];   // (D,D)
  const float* b2     = (const float*)d_in[6];   // (D,)
  const float* Wout   = (const float*)d_in[7];   // (D,2S)
  const float* bout   = (const float*)d_in[8];   // (2S,)
  float* out = (float*)d_out;

  float* ws = (float*)d_ws;
  float* q         = ws;                                   // B*D
  float* part_pool = q + (size_t)BB * DD;                  // B*SEG*D  (8 MB)
  float* part_ms   = part_pool + (size_t)BB * SEG * DD;    // B*SEG*2
  float* pool      = part_ms + (size_t)BB * SEG * 2;       // B*D

  k_q<<<BB * 8, 512, 0, stream>>>(t_star, W1, b1, W2, b2, q);
  k_fused<<<BB * SEG / 4, 256, 0, stream>>>(ctx, q, t_star, t_ctx, part_pool, part_ms);
  k_merge<<<BB * 4, 512, 0, stream>>>(part_pool, part_ms, pool);
  k_out<<<BB * 8, 256, 0, stream>>>(pool, Wout, bout, out);
}